// Round 1
// baseline (2120.072 us; speedup 1.0000x reference)
//
#include <hip/hip_runtime.h>
#include <math.h>

#define BLK 128

__global__ __launch_bounds__(BLK) void ngp_fused(
    const float* __restrict__ coords,
    const float* __restrict__ dirs,
    const float* __restrict__ table,
    const float* __restrict__ fw1, const float* __restrict__ fb1,
    const float* __restrict__ fw2, const float* __restrict__ fb2,
    const float* __restrict__ fw3, const float* __restrict__ fb3,
    const float* __restrict__ rw1, const float* __restrict__ rb1,
    const float* __restrict__ rw2, const float* __restrict__ rb2,
    const float* __restrict__ rw3, const float* __restrict__ rb3,
    const float* __restrict__ rw4, const float* __restrict__ rb4,
    float* __restrict__ out, int N)
{
    // per-thread private staging columns (no cross-thread sharing -> no barriers)
    __shared__ float sbuf[64 * BLK];
    const int tid = threadIdx.x;
    const int gi  = blockIdx.x * BLK + tid;
    if (gi >= N) return;

    constexpr int RES[16] = {32,38,46,55,67,80,97,116,140,168,203,244,294,353,425,512};
    constexpr int DN [16] = {1,1,1,1,1,1,1,1,1,1,1,1,0,0,0,0};
    constexpr int OFF[16] = {0,35937,95256,199079,374695,689127,1220568,2161760,
                             3763373,6566594,11393403,19883067,34589192,35113480,
                             35637768,36162056};
    constexpr unsigned NMASK = (1u << 19) - 1u;

    const float x = coords[3*gi+0];
    const float y = coords[3*gi+1];
    const float z = coords[3*gi+2];

    // ---------------- hash-grid encoding -> emb[32] ----------------
    float emb[32];
    #pragma unroll
    for (int l = 0; l < 16; ++l) {
        const int res = RES[l];
        const float xl = x * (float)res, yl = y * (float)res, zl = z * (float)res;
        int cx = (int)floorf(xl); cx = cx < 0 ? 0 : (cx > res-1 ? res-1 : cx);
        int cy = (int)floorf(yl); cy = cy < 0 ? 0 : (cy > res-1 ? res-1 : cy);
        int cz = (int)floorf(zl); cz = cz < 0 ? 0 : (cz > res-1 ? res-1 : cz);
        const float wx = xl - (float)cx, wy = yl - (float)cy, wz = zl - (float)cz;
        float e0 = 0.f, e1 = 0.f;
        #pragma unroll
        for (int c = 0; c < 8; ++c) {
            const int dx = (c >> 2) & 1, dy = (c >> 1) & 1, dz = c & 1;
            const float w = (dx ? wx : 1.f - wx) * (dy ? wy : 1.f - wy) * (dz ? wz : 1.f - wz);
            int idx;
            if (DN[l]) {
                idx = (cx + dx) + (cy + dy) * (res + 1) + (cz + dz) * (res + 1) * (res + 1);
            } else {
                const unsigned ux = (unsigned)(cx + dx);
                const unsigned uy = (unsigned)(cy + dy);
                const unsigned uz = (unsigned)(cz + dz);
                const unsigned hh = ux ^ (uy * 2654435761u) ^ (uz * 805459861u);
                idx = (int)(hh & NMASK);
            }
            const float2 v = *reinterpret_cast<const float2*>(table + (size_t)2 * (size_t)(OFF[l] + idx));
            e0 = fmaf(v.x, w, e0);
            e1 = fmaf(v.y, w, e1);
        }
        emb[2*l+0] = e0;
        emb[2*l+1] = e1;
    }

    float* col = sbuf + tid;

    // ---------------- f-MLP layer1: 32 -> 64, relu ----------------
    #pragma unroll 4
    for (int j = 0; j < 64; ++j) {
        float acc = fb1[j];
        #pragma unroll
        for (int i = 0; i < 32; ++i) acc = fmaf(emb[i], fw1[i*64 + j], acc);
        col[j*BLK] = fmaxf(acc, 0.f);
    }
    float h[64];
    #pragma unroll
    for (int i = 0; i < 64; ++i) h[i] = col[i*BLK];

    // ---------------- layer2: 64 -> 64, relu ----------------
    #pragma unroll 4
    for (int j = 0; j < 64; ++j) {
        float acc = fb2[j];
        #pragma unroll
        for (int i = 0; i < 64; ++i) acc = fmaf(h[i], fw2[i*64 + j], acc);
        col[j*BLK] = fmaxf(acc, 0.f);
    }
    #pragma unroll
    for (int i = 0; i < 64; ++i) h[i] = col[i*BLK];

    // ---------------- layer3: 64 -> 16, linear (feat) ----------------
    #pragma unroll 4
    for (int j = 0; j < 16; ++j) {
        float acc = fb3[j];
        #pragma unroll
        for (int i = 0; i < 64; ++i) acc = fmaf(h[i], fw3[i*16 + j], acc);
        col[j*BLK] = acc;
    }
    float f[31];
    #pragma unroll
    for (int i = 0; i < 16; ++i) f[i] = col[i*BLK];
    const float sigma = expf(f[0]);

    // ---------------- direction positional encoding -> f[16..30] ----------------
    const float dx0 = dirs[3*gi+0], dy0 = dirs[3*gi+1], dz0 = dirs[3*gi+2];
    f[16] = dx0; f[17] = dy0; f[18] = dz0;
    {
        float s, c;
        sincosf(dx0,      &s, &c); f[19] = s; f[25] = c;
        sincosf(2.f*dx0,  &s, &c); f[20] = s; f[26] = c;
        sincosf(dy0,      &s, &c); f[21] = s; f[27] = c;
        sincosf(2.f*dy0,  &s, &c); f[22] = s; f[28] = c;
        sincosf(dz0,      &s, &c); f[23] = s; f[29] = c;
        sincosf(2.f*dz0,  &s, &c); f[24] = s; f[30] = c;
    }

    // ---------------- r1: 31 -> 64, relu ----------------
    #pragma unroll 4
    for (int j = 0; j < 64; ++j) {
        float acc = rb1[j];
        #pragma unroll
        for (int i = 0; i < 31; ++i) acc = fmaf(f[i], rw1[i*64 + j], acc);
        col[j*BLK] = fmaxf(acc, 0.f);
    }
    #pragma unroll
    for (int i = 0; i < 64; ++i) h[i] = col[i*BLK];

    // ---------------- r2: 64 -> 64, relu ----------------
    #pragma unroll 4
    for (int j = 0; j < 64; ++j) {
        float acc = rb2[j];
        #pragma unroll
        for (int i = 0; i < 64; ++i) acc = fmaf(h[i], rw2[i*64 + j], acc);
        col[j*BLK] = fmaxf(acc, 0.f);
    }
    #pragma unroll
    for (int i = 0; i < 64; ++i) h[i] = col[i*BLK];

    // ---------------- r3: 64 -> 64, relu ----------------
    #pragma unroll 4
    for (int j = 0; j < 64; ++j) {
        float acc = rb3[j];
        #pragma unroll
        for (int i = 0; i < 64; ++i) acc = fmaf(h[i], rw3[i*64 + j], acc);
        col[j*BLK] = fmaxf(acc, 0.f);
    }
    #pragma unroll
    for (int i = 0; i < 64; ++i) h[i] = col[i*BLK];

    // ---------------- r4: 64 -> 3, sigmoid ----------------
    float o0 = rb4[0], o1 = rb4[1], o2 = rb4[2];
    #pragma unroll
    for (int i = 0; i < 64; ++i) {
        o0 = fmaf(h[i], rw4[i*3 + 0], o0);
        o1 = fmaf(h[i], rw4[i*3 + 1], o1);
        o2 = fmaf(h[i], rw4[i*3 + 2], o2);
    }
    o0 = 1.f / (1.f + expf(-o0));
    o1 = 1.f / (1.f + expf(-o1));
    o2 = 1.f / (1.f + expf(-o2));

    reinterpret_cast<float4*>(out)[gi] = make_float4(o0, o1, o2, sigma);
}

extern "C" void kernel_launch(void* const* d_in, const int* in_sizes, int n_in,
                              void* d_out, int out_size, void* d_ws, size_t ws_size,
                              hipStream_t stream)
{
    const float* coords = (const float*)d_in[0];
    const float* dirs   = (const float*)d_in[1];
    const float* table  = (const float*)d_in[2];
    const float* fw1 = (const float*)d_in[3];
    const float* fb1 = (const float*)d_in[4];
    const float* fw2 = (const float*)d_in[5];
    const float* fb2 = (const float*)d_in[6];
    const float* fw3 = (const float*)d_in[7];
    const float* fb3 = (const float*)d_in[8];
    const float* rw1 = (const float*)d_in[9];
    const float* rb1 = (const float*)d_in[10];
    const float* rw2 = (const float*)d_in[11];
    const float* rb2 = (const float*)d_in[12];
    const float* rw3 = (const float*)d_in[13];
    const float* rb3 = (const float*)d_in[14];
    const float* rw4 = (const float*)d_in[15];
    const float* rb4 = (const float*)d_in[16];

    const int N = in_sizes[0] / 3;
    const int grid = (N + BLK - 1) / BLK;

    hipLaunchKernelGGL(ngp_fused, dim3(grid), dim3(BLK), 0, stream,
                       coords, dirs, table,
                       fw1, fb1, fw2, fb2, fw3, fb3,
                       rw1, rb1, rw2, rb2, rw3, rb3, rw4, rb4,
                       (float*)d_out, N);
}

// Round 2
// 2057.655 us; speedup vs baseline: 1.0303x; 1.0303x over previous
//
#include <hip/hip_runtime.h>
#include <hip/hip_fp16.h>
#include <math.h>

#define BLK 128

// ---------------- table f32 -> f16 conversion (runs every call; deterministic) ----------------
__global__ __launch_bounds__(256) void cvt_table(const float4* __restrict__ src,
                                                 uint2* __restrict__ dst, int n4)
{
    int i = blockIdx.x * 256 + threadIdx.x;
    const int stride = gridDim.x * 256;
    for (; i < n4; i += stride) {
        const float4 v = src[i];
        const __half2 a = __floats2half2_rn(v.x, v.y);
        const __half2 b = __floats2half2_rn(v.z, v.w);
        uint2 o;
        o.x = *reinterpret_cast<const unsigned*>(&a);
        o.y = *reinterpret_cast<const unsigned*>(&b);
        dst[i] = o;
    }
}

// dense layer: in[NIN] regs -> out[NOUT] regs, staging through a 32-deep LDS column
template<int NIN, int NOUT, bool RELU>
__device__ __forceinline__ void dense(const float* __restrict__ W, const float* __restrict__ Bias,
                                      const float (&in)[NIN], float (&out)[NOUT], float* col)
{
    #pragma unroll
    for (int g = 0; g < NOUT; g += 32) {
        constexpr int GW = (NOUT < 32) ? NOUT : 32;
        #pragma unroll 4
        for (int j = g; j < g + GW; ++j) {
            float acc = Bias[j];
            #pragma unroll
            for (int i = 0; i < NIN; ++i) acc = fmaf(in[i], W[i * NOUT + j], acc);
            col[(j - g) * BLK] = RELU ? fmaxf(acc, 0.f) : acc;
        }
        #pragma unroll
        for (int i = g; i < g + GW; ++i) out[i] = col[(i - g) * BLK];
    }
}

template<bool HALF_TABLE>
__global__ __launch_bounds__(BLK) void ngp_fused(
    const float* __restrict__ coords,
    const float* __restrict__ dirs,
    const float* __restrict__ tableF,
    const __half2* __restrict__ tableH,
    const float* __restrict__ fw1, const float* __restrict__ fb1,
    const float* __restrict__ fw2, const float* __restrict__ fb2,
    const float* __restrict__ fw3, const float* __restrict__ fb3,
    const float* __restrict__ rw1, const float* __restrict__ rb1,
    const float* __restrict__ rw2, const float* __restrict__ rb2,
    const float* __restrict__ rw3, const float* __restrict__ rb3,
    const float* __restrict__ rw4, const float* __restrict__ rb4,
    float* __restrict__ out, int N)
{
    __shared__ float sbuf[32 * BLK];   // 16 KB/block -> up to 10 blocks/CU
    const int tid = threadIdx.x;
    const int gi  = blockIdx.x * BLK + tid;
    if (gi >= N) return;

    constexpr int RES[16] = {32,38,46,55,67,80,97,116,140,168,203,244,294,353,425,512};
    constexpr int DN [16] = {1,1,1,1,1,1,1,1,1,1,1,1,0,0,0,0};
    constexpr int OFF[16] = {0,35937,95256,199079,374695,689127,1220568,2161760,
                             3763373,6566594,11393403,19883067,34589192,35113480,
                             35637768,36162056};
    constexpr unsigned NMASK = (1u << 19) - 1u;

    const float x = coords[3*gi+0];
    const float y = coords[3*gi+1];
    const float z = coords[3*gi+2];

    // ---------------- hash-grid encoding -> emb[32] ----------------
    float emb[32];
    #pragma unroll
    for (int l = 0; l < 16; ++l) {
        const int res = RES[l];
        const float xl = x * (float)res, yl = y * (float)res, zl = z * (float)res;
        int cx = (int)floorf(xl); cx = cx < 0 ? 0 : (cx > res-1 ? res-1 : cx);
        int cy = (int)floorf(yl); cy = cy < 0 ? 0 : (cy > res-1 ? res-1 : cy);
        int cz = (int)floorf(zl); cz = cz < 0 ? 0 : (cz > res-1 ? res-1 : cz);
        const float wx = xl - (float)cx, wy = yl - (float)cy, wz = zl - (float)cz;
        float e0 = 0.f, e1 = 0.f;
        #pragma unroll
        for (int c = 0; c < 8; ++c) {
            const int dx = (c >> 2) & 1, dy = (c >> 1) & 1, dz = c & 1;
            const float w = (dx ? wx : 1.f - wx) * (dy ? wy : 1.f - wy) * (dz ? wz : 1.f - wz);
            int idx;
            if (DN[l]) {
                idx = (cx + dx) + (cy + dy) * (res + 1) + (cz + dz) * (res + 1) * (res + 1);
            } else {
                const unsigned ux = (unsigned)(cx + dx);
                const unsigned uy = (unsigned)(cy + dy);
                const unsigned uz = (unsigned)(cz + dz);
                const unsigned hh = ux ^ (uy * 2654435761u) ^ (uz * 805459861u);
                idx = (int)(hh & NMASK);
            }
            if (HALF_TABLE) {
                const __half2 v = tableH[OFF[l] + idx];
                const float2 vf = __half22float2(v);
                e0 = fmaf(vf.x, w, e0);
                e1 = fmaf(vf.y, w, e1);
            } else {
                const float2 v = *reinterpret_cast<const float2*>(tableF + (size_t)2 * (size_t)(OFF[l] + idx));
                e0 = fmaf(v.x, w, e0);
                e1 = fmaf(v.y, w, e1);
            }
        }
        emb[2*l+0] = e0;
        emb[2*l+1] = e1;
    }

    float* col = sbuf + tid;

    float A[64], B[64];
    dense<32, 64, true>(fw1, fb1, emb, A, col);   // f-layer1
    dense<64, 64, true>(fw2, fb2, A,   B, col);   // f-layer2

    float feat16[16];
    dense<64, 16, false>(fw3, fb3, B, feat16, col);   // feat
    const float sigma = expf(feat16[0]);

    // ---------------- direction positional encoding ----------------
    float f[31];
    #pragma unroll
    for (int i = 0; i < 16; ++i) f[i] = feat16[i];
    const float dx0 = dirs[3*gi+0], dy0 = dirs[3*gi+1], dz0 = dirs[3*gi+2];
    f[16] = dx0; f[17] = dy0; f[18] = dz0;
    {
        float s, c;
        sincosf(dx0,      &s, &c); f[19] = s; f[25] = c;
        sincosf(2.f*dx0,  &s, &c); f[20] = s; f[26] = c;
        sincosf(dy0,      &s, &c); f[21] = s; f[27] = c;
        sincosf(2.f*dy0,  &s, &c); f[22] = s; f[28] = c;
        sincosf(dz0,      &s, &c); f[23] = s; f[29] = c;
        sincosf(2.f*dz0,  &s, &c); f[24] = s; f[30] = c;
    }

    dense<31, 64, true>(rw1, rb1, f, A, col);     // r1
    dense<64, 64, true>(rw2, rb2, A, B, col);     // r2
    dense<64, 64, true>(rw3, rb3, B, A, col);     // r3

    // ---------------- r4: 64 -> 3, sigmoid ----------------
    float o0 = rb4[0], o1 = rb4[1], o2 = rb4[2];
    #pragma unroll
    for (int i = 0; i < 64; ++i) {
        o0 = fmaf(A[i], rw4[i*3 + 0], o0);
        o1 = fmaf(A[i], rw4[i*3 + 1], o1);
        o2 = fmaf(A[i], rw4[i*3 + 2], o2);
    }
    o0 = 1.f / (1.f + expf(-o0));
    o1 = 1.f / (1.f + expf(-o1));
    o2 = 1.f / (1.f + expf(-o2));

    reinterpret_cast<float4*>(out)[gi] = make_float4(o0, o1, o2, sigma);
}

extern "C" void kernel_launch(void* const* d_in, const int* in_sizes, int n_in,
                              void* d_out, int out_size, void* d_ws, size_t ws_size,
                              hipStream_t stream)
{
    const float* coords = (const float*)d_in[0];
    const float* dirs   = (const float*)d_in[1];
    const float* table  = (const float*)d_in[2];
    const float* fw1 = (const float*)d_in[3];
    const float* fb1 = (const float*)d_in[4];
    const float* fw2 = (const float*)d_in[5];
    const float* fb2 = (const float*)d_in[6];
    const float* fw3 = (const float*)d_in[7];
    const float* fb3 = (const float*)d_in[8];
    const float* rw1 = (const float*)d_in[9];
    const float* rb1 = (const float*)d_in[10];
    const float* rw2 = (const float*)d_in[11];
    const float* rb2 = (const float*)d_in[12];
    const float* rw3 = (const float*)d_in[13];
    const float* rb3 = (const float*)d_in[14];
    const float* rw4 = (const float*)d_in[15];
    const float* rb4 = (const float*)d_in[16];

    const int N = in_sizes[0] / 3;
    const int grid = (N + BLK - 1) / BLK;

    const int table_floats = in_sizes[2];             // total_entries * 2
    const size_t half_bytes = (size_t)table_floats * 2;  // fp16 copy size

    if (ws_size >= half_bytes) {
        __half2* tableH = (__half2*)d_ws;
        const int n4 = table_floats / 4;
        hipLaunchKernelGGL(cvt_table, dim3(2048), dim3(256), 0, stream,
                           (const float4*)table, (uint2*)d_ws, n4);
        hipLaunchKernelGGL((ngp_fused<true>), dim3(grid), dim3(BLK), 0, stream,
                           coords, dirs, table, tableH,
                           fw1, fb1, fw2, fb2, fw3, fb3,
                           rw1, rb1, rw2, rb2, rw3, rb3, rw4, rb4,
                           (float*)d_out, N);
    } else {
        hipLaunchKernelGGL((ngp_fused<false>), dim3(grid), dim3(BLK), 0, stream,
                           coords, dirs, table, (const __half2*)nullptr,
                           fw1, fb1, fw2, fb2, fw3, fb3,
                           rw1, rb1, rw2, rb2, rw3, rb3, rw4, rb4,
                           (float*)d_out, N);
    }
}